// Round 4
// baseline (30685.928 us; speedup 1.0000x reference)
//
#include <hip/hip_runtime.h>
#include <hip/hip_bf16.h>
#include <hip/hip_cooperative_groups.h>
#include <math.h>

namespace cg = cooperative_groups;

#define TT 64
#define NN 8
#define BB 128
#define DD 128
#define HH 512
#define SS 64
#define KK 16
#define AA 16
#define NB 1024
#define H3 (3*HH)       /* 1536 */

__device__ __forceinline__ float sigm(float x){ return 1.0f/(1.0f+expf(-x)); }

// ---------------- done-layout detection + mask expansion ----------------
// flag: 0 = int32, 1 = uint8/bool, 2 = float32
__global__ __launch_bounds__(256) void k_detect(const unsigned char* __restrict__ raw,
                                                int* __restrict__ flag)
{
  __shared__ int cA, cB;
  if (threadIdx.x == 0){ cA = 0; cB = 0; }
  __syncthreads();
  int a = 0, b = 0;
  for (int i = threadIdx.x; i < TT*NB; i += 256){
    unsigned char v = raw[i];
    if (v > 1) a++;
    if ((i & 3) != 0 && v != 0) b++;
  }
  atomicAdd(&cA, a); atomicAdd(&cB, b);
  __syncthreads();
  if (threadIdx.x == 0) *flag = (cB == 0) ? 0 : (cA == 0 ? 1 : 2);
}

__global__ __launch_bounds__(256) void k_mask(const unsigned char* __restrict__ raw,
                                              const int* __restrict__ flag,
                                              float* __restrict__ mask)
{
  int i = blockIdx.x*256 + threadIdx.x;
  if (i >= TT*NB) return;
  int f = *flag;
  int v;
  if (f == 1)      v = (int)raw[i];
  else if (f == 0) v = ((const int*)raw)[i];
  else             v = (((const float*)raw)[i] != 0.0f);
  mask[i] = v ? 0.f : 1.f;   // 0 => reset carry
}

// ---------------- small setup kernels ----------------

__global__ __launch_bounds__(256) void k_e(const float* __restrict__ W_e1, const float* __restrict__ b_e1,
                                           const float* __restrict__ W_e2, const float* __restrict__ b_e2,
                                           float* __restrict__ e_out)
{
  __shared__ float r1[KK*SS];
  int tid = threadIdx.x;
  for (int i=0;i<4;++i){ int l = tid + i*256; float v = W_e1[l] + b_e1[l & 63]; r1[l] = v > 0.f ? v : 0.f; }
  __syncthreads();
  for (int i=0;i<4;++i){
    int l = tid + i*256; int k = l >> 6, s = l & 63;
    float acc = b_e2[s];
    #pragma unroll 8
    for (int sp=0; sp<64; ++sp) acc += r1[k*64+sp] * W_e2[sp*64 + s];
    e_out[l] = tanhf(acc);
  }
}

__global__ __launch_bounds__(256) void k_w1b1(const float* __restrict__ e, const float* __restrict__ W_w1,
                                              const float* __restrict__ b_w1, const float* __restrict__ W_b1,
                                              const float* __restrict__ b_b1, float* __restrict__ w1,
                                              float* __restrict__ b1)
{
  __shared__ float es[KK*SS];
  int tid = threadIdx.x;
  for (int i=0;i<4;++i) es[tid + i*256] = e[tid + i*256];
  __syncthreads();
  for (int i=0;i<4;++i){
    int l = blockIdx.x*1024 + tid + i*256;
    int k = l >> 13, m = l & 8191;
    float acc = b_w1[m];
    #pragma unroll 8
    for (int s=0;s<64;++s) acc += es[k*64+s] * W_w1[(size_t)s*8192 + m];
    w1[l] = acc;
  }
  if (blockIdx.x == 0){
    int k = tid >> 4, a = tid & 15;
    float acc = b_b1[a];
    #pragma unroll 8
    for (int s=0;s<64;++s) acc += es[k*64+s] * W_b1[s*16 + a];
    b1[tid] = acc;
  }
}

__global__ __launch_bounds__(256) void k_se(const float* __restrict__ e, float* __restrict__ outse)
{
  __shared__ float4 es[256];
  es[threadIdx.x] = ((const float4*)e)[threadIdx.x];
  __syncthreads();
  const int total4 = TT*BB*KK*SS/4;
  for (int i = blockIdx.x*256 + threadIdx.x; i < total4; i += gridDim.x*256)
    ((float4*)outse)[i] = es[i & 255];
}

__global__ void k_copy(const float* __restrict__ src, float* __restrict__ dst, int n4)
{
  int i = blockIdx.x*blockDim.x + threadIdx.x;
  if (i < n4) ((float4*)dst)[i] = ((const float4*)src)[i];
}

// ---------------- generic tiled f32 GEMM: C = act(A@W + bias) ----------------
template<int RELU>
__global__ __launch_bounds__(256) void gemm_bias_act(
    const float* __restrict__ A, const float* __restrict__ W,
    const float* __restrict__ bias, float* __restrict__ C,
    int M, int Kd, int Nc)
{
  __shared__ float As[16][72];
  __shared__ float Bs[16][72];
  int tid = threadIdx.x;
  int tx = tid & 15, ty = tid >> 4;
  int rowBase = blockIdx.y * 64;
  int colBase = blockIdx.x * 64;
  float acc[4][4] = {};
  for (int k0 = 0; k0 < Kd; k0 += 16){
    {
      int r  = tid >> 2;
      int kb = (tid & 3) * 4;
      float4 v = *(const float4*)&A[(size_t)(rowBase + r)*Kd + k0 + kb];
      As[kb+0][r]=v.x; As[kb+1][r]=v.y; As[kb+2][r]=v.z; As[kb+3][r]=v.w;
    }
    #pragma unroll
    for (int i=0;i<4;++i){
      int l = i*256 + tid;
      int kk = l >> 6, c = l & 63;
      Bs[kk][c] = W[(size_t)(k0+kk)*Nc + colBase + c];
    }
    __syncthreads();
    #pragma unroll
    for (int kk=0;kk<16;++kk){
      float4 a4 = *(const float4*)&As[kk][ty*4];
      float4 b4 = *(const float4*)&Bs[kk][tx*4];
      float av[4]={a4.x,a4.y,a4.z,a4.w}, bv[4]={b4.x,b4.y,b4.z,b4.w};
      #pragma unroll
      for (int i=0;i<4;++i)
        #pragma unroll
        for (int j=0;j<4;++j) acc[i][j] += av[i]*bv[j];
    }
    __syncthreads();
  }
  int c0 = colBase + tx*4;
  float4 bv4 = *(const float4*)&bias[c0];
  float bb[4]={bv4.x,bv4.y,bv4.z,bv4.w};
  for (int i=0;i<4;++i){
    int r = rowBase + ty*4 + i;
    float o[4];
    #pragma unroll
    for (int j=0;j<4;++j){ float v = acc[i][j] + bb[j]; if (RELU) v = v>0.f?v:0.f; o[j]=v; }
    *(float4*)&C[(size_t)r*Nc + c0] = make_float4(o[0],o[1],o[2],o[3]);
  }
}

// ---------------- per-step GRU (fallback path, verified in round 2) ----------------
__global__ __launch_bounds__(256) void gru_step(
    const float* __restrict__ hprev, const float* __restrict__ gi,
    const float* __restrict__ Wh, const float* __restrict__ bhn,
    const float* __restrict__ mask_t, float* __restrict__ hout)
{
  __shared__ float hs[16][17];
  __shared__ float Wsh[3][16][68];
  __shared__ float dms[16];
  int tid = threadIdx.x;
  int tx = tid & 15, ty = tid >> 4;
  int colBase = blockIdx.x * 64;
  int rowBase = blockIdx.y * 16;
  if (tid < 16) dms[tid] = mask_t[rowBase + tid];
  __syncthreads();
  float accR[4]={0,0,0,0}, accZ[4]={0,0,0,0}, accN[4]={0,0,0,0};
  for (int k0=0;k0<HH;k0+=16){
    {
      int row = tid >> 4, kk = tid & 15;
      hs[row][kk] = hprev[(size_t)(rowBase+row)*HH + k0 + kk] * dms[row];
    }
    #pragma unroll
    for (int g=0; g<3; ++g){
      int cb = g*HH + colBase;
      #pragma unroll
      for (int i=0;i<4;++i){
        int l = i*256 + tid;
        int kk = l >> 6, c = l & 63;
        Wsh[g][kk][c] = Wh[(size_t)(k0+kk)*H3 + cb + c];
      }
    }
    __syncthreads();
    #pragma unroll
    for (int kk=0;kk<16;++kk){
      float a = hs[ty][kk];
      float4 wr = *(const float4*)&Wsh[0][kk][tx*4];
      float4 wz = *(const float4*)&Wsh[1][kk][tx*4];
      float4 wn = *(const float4*)&Wsh[2][kk][tx*4];
      accR[0]+=a*wr.x; accR[1]+=a*wr.y; accR[2]+=a*wr.z; accR[3]+=a*wr.w;
      accZ[0]+=a*wz.x; accZ[1]+=a*wz.y; accZ[2]+=a*wz.z; accZ[3]+=a*wz.w;
      accN[0]+=a*wn.x; accN[1]+=a*wn.y; accN[2]+=a*wn.z; accN[3]+=a*wn.w;
    }
    __syncthreads();
  }
  int jrow = rowBase + ty;
  int c0 = colBase + tx*4;
  size_t gb = (size_t)jrow*H3 + c0;
  float4 gr = *(const float4*)&gi[gb];
  float4 gz = *(const float4*)&gi[gb + HH];
  float4 gn = *(const float4*)&gi[gb + 2*HH];
  float4 bn4 = *(const float4*)&bhn[c0];
  float dm = dms[ty];
  float4 hp4 = *(const float4*)&hprev[(size_t)jrow*HH + c0];
  float hpv[4]={hp4.x*dm,hp4.y*dm,hp4.z*dm,hp4.w*dm};
  float grv[4]={gr.x,gr.y,gr.z,gr.w};
  float gzv[4]={gz.x,gz.y,gz.z,gz.w};
  float gnv[4]={gn.x,gn.y,gn.z,gn.w};
  float bnv[4]={bn4.x,bn4.y,bn4.z,bn4.w};
  float o[4];
  #pragma unroll
  for (int j=0;j<4;++j){
    float rg = sigm(grv[j] + accR[j]);
    float zg = sigm(gzv[j] + accZ[j]);
    float ng = tanhf(gnv[j] + rg*(accN[j] + bnv[j]));
    o[j] = (1.f - zg)*ng + zg*hpv[j];
  }
  *(float4*)&hout[(size_t)jrow*HH + c0] = make_float4(o[0],o[1],o[2],o[3]);
}

// ---------------- persistent cooperative dual-GRU scan (42KB static LDS) ----------------
// 256 blocks x 256 thr, 1 block/CU. block: gru = b>>7; cb = (b&127)&31 (16 cols); rb = (b&127)>>5 (256 rows).
// Wh is streamed from L2 in 32-k chunks (6KB LDS); h slice staged in hs (36KB).
__global__ __launch_bounds__(256, 1) void gru_scan(
    float* __restrict__ buf1, float* __restrict__ buf2,
    const float* __restrict__ gbuf1, const float* __restrict__ gbuf2,
    const float* __restrict__ Wh1, const float* __restrict__ Wh2,
    const float* __restrict__ bhn1, const float* __restrict__ bhn2,
    float* __restrict__ h_last1, float* __restrict__ h_last2,
    const float* __restrict__ mask, int t0, int CH)
{
  __shared__ float Wsh[32][48];    // k-chunk of Wh slice: [kk][ci*3+g]
  __shared__ float hs[256][36];    // staged h rows (36-pad)
  cg::grid_group grid = cg::this_grid();

  int b   = blockIdx.x;
  int gru = b >> 7, sub = b & 127;
  int cb  = sub & 31, rb = sub >> 5;
  int rowBase = rb << 8;
  int colBase = cb << 4;
  int tid = threadIdx.x;
  int tx = tid & 15, ty = tid >> 4;

  float*       buf   = gru ? buf2   : buf1;
  const float* gbuf  = gru ? gbuf2  : gbuf1;
  const float* Wh    = gru ? Wh2    : Wh1;
  const float* bhnp  = gru ? bhn2   : bhn1;
  float*       hlast = gru ? h_last2: h_last1;

  float bhn_c = bhnp[colBase + tx];
  int   c     = colBase + tx;
  int   capk  = colBase & ~31;     // which k-chunk holds this block's own columns

  for (int lt = 0; lt < CH; ++lt){
    const float* hp = lt ? (buf + (size_t)(lt-1)*NB*HH) : hlast;
    float m = mask[(size_t)(t0+lt)*NB + rowBase + tid];   // mask for the row THIS thread stages
    float acc[16][3];
    #pragma unroll
    for (int i=0;i<16;++i){ acc[i][0]=0.f; acc[i][1]=0.f; acc[i][2]=0.f; }
    float hval[16];

    for (int k0 = 0; k0 < HH; k0 += 32){
      __syncthreads();   // protect hs/Wsh from previous chunk's readers
      // stage masked h rows [rowBase..rowBase+256) x cols [k0..k0+32)
      {
        const float4* src = (const float4*)&hp[(size_t)(rowBase + tid)*HH + k0];
        float4* dst = (float4*)&hs[tid][0];
        #pragma unroll
        for (int q=0;q<8;++q){
          float4 v = src[q];
          v.x*=m; v.y*=m; v.z*=m; v.w*=m;
          dst[q] = v;
        }
      }
      // stage Wh chunk: 32k x 16cols x 3gates = 1536 floats
      #pragma unroll
      for (int j=0;j<6;++j){
        int lin = j*256 + tid;             // 0..1535
        int ci  = lin & 15;
        int r48 = lin % 48;
        int g   = r48 >> 4;
        int kk  = lin / 48;
        Wsh[kk][ci*3+g] = Wh[(size_t)(k0+kk)*H3 + g*HH + colBase + ci];
      }
      __syncthreads();
      if (k0 == capk){                     // capture masked h_prev at this block's own columns
        int off = c - k0;
        #pragma unroll
        for (int i=0;i<16;++i) hval[i] = hs[i*16+ty][off];
      }
      #pragma unroll
      for (int kk = 0; kk < 32; kk += 4){
        float w[4][3];
        #pragma unroll
        for (int q=0;q<4;++q){
          w[q][0]=Wsh[kk+q][tx*3+0]; w[q][1]=Wsh[kk+q][tx*3+1]; w[q][2]=Wsh[kk+q][tx*3+2];
        }
        #pragma unroll
        for (int i=0;i<16;++i){
          float4 a4 = *(const float4*)&hs[i*16+ty][kk];
          acc[i][0] += a4.x*w[0][0] + a4.y*w[1][0] + a4.z*w[2][0] + a4.w*w[3][0];
          acc[i][1] += a4.x*w[0][1] + a4.y*w[1][1] + a4.z*w[2][1] + a4.w*w[3][1];
          acc[i][2] += a4.x*w[0][2] + a4.y*w[1][2] + a4.z*w[2][2] + a4.w*w[3][2];
        }
      }
    }

    #pragma unroll
    for (int i=0;i<16;++i){
      int row = rowBase + i*16 + ty;
      size_t gbase = ((size_t)lt*NB + row)*H3 + c;
      float gr = gbuf[gbase], gz = gbuf[gbase+HH], gn = gbuf[gbase+2*HH];
      float rg = sigm(gr + acc[i][0]);
      float zg = sigm(gz + acc[i][1]);
      float ng = tanhf(gn + rg*(acc[i][2] + bhn_c));
      float o  = (1.f-zg)*ng + zg*hval[i];
      buf[((size_t)lt*NB + row)*HH + c] = o;
      if (lt == CH-1) hlast[(size_t)row*HH + c] = o;
    }
    if (lt != CH-1){ __threadfence(); grid.sync(); }
  }
}

// ---------------- logits + first-max argmax (chunked: t = t0 + local) ----------------
__global__ __launch_bounds__(256) void k_logits(const float* __restrict__ ae2,
    const float* __restrict__ e, float* __restrict__ out_logits, int* __restrict__ argk, int t0)
{
  __shared__ float es[KK*SS];
  int tid = threadIdx.x;
  for (int i=0;i<4;++i) es[tid + i*256] = e[tid + i*256];
  __syncthreads();
  int g = blockIdx.x*256 + tid;
  int t = t0 + (g >> 10), j = g & 1023;
  const float* arow = &ae2[(size_t)g * SS];
  float a[SS];
  #pragma unroll
  for (int i=0;i<16;++i){ float4 v = ((const float4*)arow)[i]; a[4*i]=v.x; a[4*i+1]=v.y; a[4*i+2]=v.z; a[4*i+3]=v.w; }
  float lg[KK];
  float best = -INFINITY; int bk = 0;
  for (int k=0;k<KK;++k){
    float s2 = 0.f;
    #pragma unroll 8
    for (int s=0;s<SS;++s) s2 += a[s]*es[k*SS+s];
    lg[k] = s2;
    if (s2 > best){ best = s2; bk = k; }
  }
  int n = j >> 7, b = j & 127;
  size_t ob = ((size_t)((t*BB + b)*NN + n)) * KK;
  #pragma unroll
  for (int k4=0;k4<4;++k4)
    *(float4*)&out_logits[ob + k4*4] = make_float4(lg[k4*4],lg[k4*4+1],lg[k4*4+2],lg[k4*4+3]);
  argk[(t*BB + b)*NN + n] = bk;   // stored (b,n)-major: matches reference's prob/q index quirk
}

// ---------------- q selection (chunked) ----------------
__global__ __launch_bounds__(64) void k_qsel(const float* __restrict__ y2,
    const float* __restrict__ w1, const float* __restrict__ b1,
    const int* __restrict__ argk, float* __restrict__ outq)
{
  __shared__ float yr[HH];
  __shared__ float part[64];
  int bj = blockIdx.x;
  int tid = threadIdx.x;
  const float4* row4 = (const float4*)&y2[(size_t)bj*HH];
  ((float4*)yr)[tid]    = row4[tid];
  ((float4*)yr)[tid+64] = row4[tid+64];
  __syncthreads();
  int k = argk[bj];
  int a = tid & 15, q4 = tid >> 4;
  const float* wp = &w1[(size_t)k*HH*AA + a];
  float s = 0.f;
  int h0 = q4*128;
  #pragma unroll 8
  for (int h=h0; h<h0+128; ++h) s += yr[h]*wp[(size_t)h*AA];
  part[tid] = s;
  __syncthreads();
  if (q4 == 0){
    float v = part[a] + part[a+16] + part[a+32] + part[a+48] + b1[k*AA + a];
    outq[(size_t)bj*AA + a] = v;
  }
}

// ---------------- orchestration ----------------
extern "C" void kernel_launch(void* const* d_in, const int* in_sizes, int n_in,
                              void* d_out, int out_size, void* d_ws, size_t ws_size,
                              hipStream_t stream)
{
  (void)in_sizes; (void)n_in; (void)out_size;
  const float* h1     = (const float*)d_in[0];
  const float* h2     = (const float*)d_in[1];
  const float* obs    = (const float*)d_in[2];
  const unsigned char* done_raw = (const unsigned char*)d_in[3];
  const float* W_embed=(const float*)d_in[4];  const float* b_embed=(const float*)d_in[5];
  const float* Wi1    =(const float*)d_in[6];  const float* bi1    =(const float*)d_in[7];
  const float* Wh1    =(const float*)d_in[8];  const float* bhn1   =(const float*)d_in[9];
  const float* W_sub  =(const float*)d_in[10]; const float* b_sub  =(const float*)d_in[11];
  const float* W_e1   =(const float*)d_in[12]; const float* b_e1   =(const float*)d_in[13];
  const float* W_e2   =(const float*)d_in[14]; const float* b_e2   =(const float*)d_in[15];
  const float* W_pol  =(const float*)d_in[16]; const float* b_pol  =(const float*)d_in[17];
  const float* Wi2    =(const float*)d_in[18]; const float* bi2    =(const float*)d_in[19];
  const float* Wh2    =(const float*)d_in[20]; const float* bhn2   =(const float*)d_in[21];
  const float* W_w1   =(const float*)d_in[22]; const float* b_w1   =(const float*)d_in[23];
  const float* W_b1   =(const float*)d_in[24]; const float* b_b1   =(const float*)d_in[25];

  float* out    = (float*)d_out;
  float* outHT1 = out;
  float* outHT2 = out + (size_t)NB*HH;
  float* outQ   = out + 2ull*NB*HH;
  float* outLG  = outQ + (size_t)TT*NB*AA;
  float* outSE  = outLG + (size_t)TT*BB*NN*KK;

  // ---- adaptive chunk size from ws_size ----
  const size_t fixed_f = 2ull*NB*HH /*h_last1,2*/ + (size_t)TT*NB /*mask*/ + 1024 /*e*/
                       + (size_t)KK*HH*AA /*w1*/ + 256 /*b1*/ + (size_t)TT*NB /*argk*/ + 64 /*flag*/;
  const size_t per_t_f = (size_t)NB*(2*HH + 2*H3 + SS);
  int CH = 64;
  while (CH > 1 && (fixed_f + per_t_f*(size_t)CH)*4 > ws_size) CH >>= 1;

  float* buf1   = (float*)d_ws;                        // ae1/y1 chunk: CH*NB*HH
  float* buf2   = buf1   + (size_t)CH*NB*HH;           // sp/y2 chunk
  float* gbuf1  = buf2   + (size_t)CH*NB*HH;           // gi1 chunk: CH*NB*H3
  float* gbuf2  = gbuf1  + (size_t)CH*NB*H3;           // gi2 chunk
  float* ae2buf = gbuf2  + (size_t)CH*NB*H3;           // CH*NB*SS
  float* h_last1= ae2buf + (size_t)CH*NB*SS;
  float* h_last2= h_last1+ (size_t)NB*HH;
  float* maskp  = h_last2+ (size_t)NB*HH;
  float* ws_e   = maskp  + (size_t)TT*NB;
  float* ws_w1  = ws_e   + 1024;
  float* ws_b1  = ws_w1  + (size_t)KK*HH*AA;
  int*   ws_argk= (int*)(ws_b1 + 256);
  int*   ws_flag= (int*)(ws_argk + (size_t)TT*NB);

  // phase 0
  k_detect<<<1,256,0,stream>>>(done_raw, ws_flag);
  k_mask<<<TT*NB/256,256,0,stream>>>(done_raw, ws_flag, maskp);
  k_e<<<1,256,0,stream>>>(W_e1,b_e1,W_e2,b_e2,ws_e);
  k_w1b1<<<128,256,0,stream>>>(ws_e,W_w1,b_w1,W_b1,b_b1,ws_w1,ws_b1);
  k_se<<<2048,256,0,stream>>>(ws_e,outSE);
  k_copy<<<512,256,0,stream>>>(h1, h_last1, NB*HH/4);
  k_copy<<<512,256,0,stream>>>(h2, h_last2, NB*HH/4);

  dim3 thr(256);
  const int NCH = TT / CH;
  for (int c = 0; c < NCH; ++c){
    int t0 = c * CH;
    const float* obs_c = obs + (size_t)t0*NB*DD;
    gemm_bias_act<1><<<dim3(HH/64, CH*NB/64),thr,0,stream>>>(obs_c, W_embed, b_embed, buf1, CH*NB, DD, HH);
    gemm_bias_act<0><<<dim3(H3/64, CH*NB/64),thr,0,stream>>>(buf1, Wi1, bi1, gbuf1, CH*NB, HH, H3);
    gemm_bias_act<1><<<dim3(HH/64, CH*NB/64),thr,0,stream>>>(obs_c, W_pol, b_pol, buf2, CH*NB, DD, HH);
    gemm_bias_act<0><<<dim3(H3/64, CH*NB/64),thr,0,stream>>>(buf2, Wi2, bi2, gbuf2, CH*NB, HH, H3);
    // dual-GRU persistent scan for CH steps; fallback to per-step kernels if coop launch fails
    {
      int t0v = t0, CHv = CH;
      void* args[] = { &buf1, &buf2, (void*)&gbuf1, (void*)&gbuf2,
                       (void*)&Wh1, (void*)&Wh2, (void*)&bhn1, (void*)&bhn2,
                       &h_last1, &h_last2, (void*)&maskp, &t0v, &CHv };
      hipError_t cerr = hipLaunchCooperativeKernel((const void*)gru_scan, dim3(256), dim3(256),
                                                   args, 0, stream);
      if (cerr != hipSuccess){
        (void)hipGetLastError();   // clear sticky error, use verified per-step path
        for (int lt = 0; lt < CH; ++lt){
          const float* hp1 = (lt == 0) ? h_last1 : (buf1 + (size_t)(lt-1)*NB*HH);
          const float* hp2 = (lt == 0) ? h_last2 : (buf2 + (size_t)(lt-1)*NB*HH);
          gru_step<<<dim3(HH/64, NB/16),thr,0,stream>>>(hp1, gbuf1 + (size_t)lt*NB*H3, Wh1, bhn1,
                                                        maskp + (size_t)(t0+lt)*NB, buf1 + (size_t)lt*NB*HH);
          gru_step<<<dim3(HH/64, NB/16),thr,0,stream>>>(hp2, gbuf2 + (size_t)lt*NB*H3, Wh2, bhn2,
                                                        maskp + (size_t)(t0+lt)*NB, buf2 + (size_t)lt*NB*HH);
        }
        k_copy<<<512,256,0,stream>>>(buf1 + (size_t)(CH-1)*NB*HH, h_last1, NB*HH/4);
        k_copy<<<512,256,0,stream>>>(buf2 + (size_t)(CH-1)*NB*HH, h_last2, NB*HH/4);
      }
    }
    gemm_bias_act<0><<<dim3(SS/64, CH*NB/64),thr,0,stream>>>(buf1, W_sub, b_sub, ae2buf, CH*NB, HH, SS);
    k_logits<<<CH*NB/256,256,0,stream>>>(ae2buf, ws_e, outLG, ws_argk, t0);
    k_qsel<<<CH*NB,64,0,stream>>>(buf2, ws_w1, ws_b1, ws_argk + (size_t)t0*NB, outQ + (size_t)t0*NB*AA);
  }
  k_copy<<<512,256,0,stream>>>(h_last1, outHT1, NB*HH/4);
  k_copy<<<512,256,0,stream>>>(h_last2, outHT2, NB*HH/4);
}

// Round 5
// 9917.129 us; speedup vs baseline: 3.0942x; 3.0942x over previous
//
#include <hip/hip_runtime.h>
#include <hip/hip_bf16.h>
#include <math.h>

#define TT 64
#define NN 8
#define BB 128
#define DD 128
#define HH 512
#define SS 64
#define KK 16
#define AA 16
#define NB 1024
#define H3 (3*HH)       /* 1536 */

__device__ __forceinline__ float sigm(float x){ return 1.0f/(1.0f+expf(-x)); }

// ---------------- done-layout detection + mask expansion ----------------
// flag: 0 = int32, 1 = uint8/bool, 2 = float32
__global__ __launch_bounds__(256) void k_detect(const unsigned char* __restrict__ raw,
                                                int* __restrict__ flag)
{
  __shared__ int cA, cB;
  if (threadIdx.x == 0){ cA = 0; cB = 0; }
  __syncthreads();
  int a = 0, b = 0;
  for (int i = threadIdx.x; i < TT*NB; i += 256){
    unsigned char v = raw[i];
    if (v > 1) a++;
    if ((i & 3) != 0 && v != 0) b++;
  }
  atomicAdd(&cA, a); atomicAdd(&cB, b);
  __syncthreads();
  if (threadIdx.x == 0) *flag = (cB == 0) ? 0 : (cA == 0 ? 1 : 2);
}

__global__ __launch_bounds__(256) void k_mask(const unsigned char* __restrict__ raw,
                                              const int* __restrict__ flag,
                                              float* __restrict__ mask)
{
  int i = blockIdx.x*256 + threadIdx.x;
  if (i >= TT*NB) return;
  int f = *flag;
  int v;
  if (f == 1)      v = (int)raw[i];
  else if (f == 0) v = ((const int*)raw)[i];
  else             v = (((const float*)raw)[i] != 0.0f);
  mask[i] = v ? 0.f : 1.f;   // 0 => reset carry
}

// ---------------- small setup kernels ----------------

__global__ __launch_bounds__(256) void k_e(const float* __restrict__ W_e1, const float* __restrict__ b_e1,
                                           const float* __restrict__ W_e2, const float* __restrict__ b_e2,
                                           float* __restrict__ e_out)
{
  __shared__ float r1[KK*SS];
  int tid = threadIdx.x;
  for (int i=0;i<4;++i){ int l = tid + i*256; float v = W_e1[l] + b_e1[l & 63]; r1[l] = v > 0.f ? v : 0.f; }
  __syncthreads();
  for (int i=0;i<4;++i){
    int l = tid + i*256; int k = l >> 6, s = l & 63;
    float acc = b_e2[s];
    #pragma unroll 8
    for (int sp=0; sp<64; ++sp) acc += r1[k*64+sp] * W_e2[sp*64 + s];
    e_out[l] = tanhf(acc);
  }
}

__global__ __launch_bounds__(256) void k_w1b1(const float* __restrict__ e, const float* __restrict__ W_w1,
                                              const float* __restrict__ b_w1, const float* __restrict__ W_b1,
                                              const float* __restrict__ b_b1, float* __restrict__ w1,
                                              float* __restrict__ b1)
{
  __shared__ float es[KK*SS];
  int tid = threadIdx.x;
  for (int i=0;i<4;++i) es[tid + i*256] = e[tid + i*256];
  __syncthreads();
  for (int i=0;i<4;++i){
    int l = blockIdx.x*1024 + tid + i*256;
    int k = l >> 13, m = l & 8191;
    float acc = b_w1[m];
    #pragma unroll 8
    for (int s=0;s<64;++s) acc += es[k*64+s] * W_w1[(size_t)s*8192 + m];
    w1[l] = acc;
  }
  if (blockIdx.x == 0){
    int k = tid >> 4, a = tid & 15;
    float acc = b_b1[a];
    #pragma unroll 8
    for (int s=0;s<64;++s) acc += es[k*64+s] * W_b1[s*16 + a];
    b1[tid] = acc;
  }
}

__global__ __launch_bounds__(256) void k_se(const float* __restrict__ e, float* __restrict__ outse)
{
  __shared__ float4 es[256];
  es[threadIdx.x] = ((const float4*)e)[threadIdx.x];
  __syncthreads();
  const int total4 = TT*BB*KK*SS/4;
  for (int i = blockIdx.x*256 + threadIdx.x; i < total4; i += gridDim.x*256)
    ((float4*)outse)[i] = es[i & 255];
}

__global__ void k_copy(const float* __restrict__ src, float* __restrict__ dst, int n4)
{
  int i = blockIdx.x*blockDim.x + threadIdx.x;
  if (i < n4) ((float4*)dst)[i] = ((const float4*)src)[i];
}

// ---------------- generic tiled f32 GEMM: C = act(A@W + bias) ----------------
template<int RELU>
__global__ __launch_bounds__(256) void gemm_bias_act(
    const float* __restrict__ A, const float* __restrict__ W,
    const float* __restrict__ bias, float* __restrict__ C,
    int M, int Kd, int Nc)
{
  __shared__ float As[16][72];
  __shared__ float Bs[16][72];
  int tid = threadIdx.x;
  int tx = tid & 15, ty = tid >> 4;
  int rowBase = blockIdx.y * 64;
  int colBase = blockIdx.x * 64;
  float acc[4][4] = {};
  for (int k0 = 0; k0 < Kd; k0 += 16){
    {
      int r  = tid >> 2;
      int kb = (tid & 3) * 4;
      float4 v = *(const float4*)&A[(size_t)(rowBase + r)*Kd + k0 + kb];
      As[kb+0][r]=v.x; As[kb+1][r]=v.y; As[kb+2][r]=v.z; As[kb+3][r]=v.w;
    }
    #pragma unroll
    for (int i=0;i<4;++i){
      int l = i*256 + tid;
      int kk = l >> 6, c = l & 63;
      Bs[kk][c] = W[(size_t)(k0+kk)*Nc + colBase + c];
    }
    __syncthreads();
    #pragma unroll
    for (int kk=0;kk<16;++kk){
      float4 a4 = *(const float4*)&As[kk][ty*4];
      float4 b4 = *(const float4*)&Bs[kk][tx*4];
      float av[4]={a4.x,a4.y,a4.z,a4.w}, bv[4]={b4.x,b4.y,b4.z,b4.w};
      #pragma unroll
      for (int i=0;i<4;++i)
        #pragma unroll
        for (int j=0;j<4;++j) acc[i][j] += av[i]*bv[j];
    }
    __syncthreads();
  }
  int c0 = colBase + tx*4;
  float4 bv4 = *(const float4*)&bias[c0];
  float bb[4]={bv4.x,bv4.y,bv4.z,bv4.w};
  for (int i=0;i<4;++i){
    int r = rowBase + ty*4 + i;
    float o[4];
    #pragma unroll
    for (int j=0;j<4;++j){ float v = acc[i][j] + bb[j]; if (RELU) v = v>0.f?v:0.f; o[j]=v; }
    *(float4*)&C[(size_t)r*Nc + c0] = make_float4(o[0],o[1],o[2],o[3]);
  }
}

// ---------------- per-step dual-GRU kernel ----------------
// Grid 256 blocks x 512 thr. gru = bid>>7; sub = bid&127: cb = sub&15 (32 cols), rb = sub>>4 (128 rows).
// Per thread: tx = tid&31 (col), ty = tid>>5 (0..15); owns rows rb*128 + i*16 + ty, i<8. 24 accs.
// h staged masked in LDS per 32-k chunk; Wh chunk streamed to LDS; gi read nontemporal (don't evict h/Wh from L2).
__global__ __launch_bounds__(512, 2) void gru_step2(
    const float* __restrict__ hp1, const float* __restrict__ hp2,
    const float* __restrict__ gi1, const float* __restrict__ gi2,
    const float* __restrict__ Wh1, const float* __restrict__ Wh2,
    const float* __restrict__ bhn1, const float* __restrict__ bhn2,
    const float* __restrict__ mask_t,
    float* __restrict__ ho1, float* __restrict__ ho2)
{
  __shared__ float hs[128][36];       // staged masked h rows x 32-k chunk (f4-aligned, 2 addrs/wave reads)
  __shared__ float Wsh[3][32][33];    // Wh chunk [gate][kk][col] (scalar broadcast reads, conflict-free)

  int bid = blockIdx.x;
  int gru = bid >> 7, sub = bid & 127;
  int cb  = sub & 15, rb = sub >> 4;
  int rowBase = rb << 7;              // 128 rows
  int colBase = cb << 5;              // 32 cols
  int tid = threadIdx.x;
  int tx = tid & 31, ty = tid >> 5;

  const float* hp   = gru ? hp2  : hp1;
  const float* gi   = gru ? gi2  : gi1;
  const float* Wh   = gru ? Wh2  : Wh1;
  const float* bhnp = gru ? bhn2 : bhn1;
  float*       ho   = gru ? ho2  : ho1;

  int   r  = tid >> 2;                 // staging row (0..127)
  int   q  = tid & 3;                  // staging 8-float group
  float m  = mask_t[rowBase + r];      // reset mask for the staged row

  float acc[8][3];
  #pragma unroll
  for (int i=0;i<8;++i){ acc[i][0]=0.f; acc[i][1]=0.f; acc[i][2]=0.f; }
  float hval[8];

  for (int k0 = 0; k0 < HH; k0 += 32){
    __syncthreads();
    // stage masked h chunk: 128 rows x 32 k
    {
      const float4* src = (const float4*)&hp[(size_t)(rowBase + r)*HH + k0 + q*8];
      float4 v0 = src[0], v1 = src[1];
      v0.x*=m; v0.y*=m; v0.z*=m; v0.w*=m;
      v1.x*=m; v1.y*=m; v1.z*=m; v1.w*=m;
      float4* dst = (float4*)&hs[r][q*8];
      dst[0] = v0; dst[1] = v1;
    }
    // stage Wh chunk: 32 k x 32 cols x 3 gates = 3072 floats (128B-coalesced segments)
    #pragma unroll
    for (int j=0;j<6;++j){
      int lin = j*512 + tid;
      int g = lin >> 10, rem = lin & 1023, kk = rem >> 5, ci = rem & 31;
      Wsh[g][kk][ci] = Wh[(size_t)(k0+kk)*H3 + g*HH + colBase + ci];
    }
    __syncthreads();
    if (k0 == colBase){                // this chunk holds the block's own columns
      #pragma unroll
      for (int i=0;i<8;++i) hval[i] = hs[i*16+ty][tx];
    }
    #pragma unroll
    for (int kk = 0; kk < 32; kk += 4){
      float wr[4], wz[4], wn[4];
      #pragma unroll
      for (int p=0;p<4;++p){ wr[p]=Wsh[0][kk+p][tx]; wz[p]=Wsh[1][kk+p][tx]; wn[p]=Wsh[2][kk+p][tx]; }
      #pragma unroll
      for (int i=0;i<8;++i){
        float4 a4 = *(const float4*)&hs[i*16+ty][kk];
        acc[i][0] += a4.x*wr[0] + a4.y*wr[1] + a4.z*wr[2] + a4.w*wr[3];
        acc[i][1] += a4.x*wz[0] + a4.y*wz[1] + a4.z*wz[2] + a4.w*wz[3];
        acc[i][2] += a4.x*wn[0] + a4.y*wn[1] + a4.z*wn[2] + a4.w*wn[3];
      }
    }
  }

  int c = colBase + tx;
  float bhn_c = bhnp[c];
  #pragma unroll
  for (int i=0;i<8;++i){
    int row = rowBase + i*16 + ty;
    size_t gb = (size_t)row*H3 + c;
    float gr = __builtin_nontemporal_load(&gi[gb]);
    float gz = __builtin_nontemporal_load(&gi[gb + HH]);
    float gn = __builtin_nontemporal_load(&gi[gb + 2*HH]);
    float rg = sigm(gr + acc[i][0]);
    float zg = sigm(gz + acc[i][1]);
    float ng = tanhf(gn + rg*(acc[i][2] + bhn_c));
    ho[(size_t)row*HH + c] = (1.f - zg)*ng + zg*hval[i];
  }
}

// ---------------- logits + first-max argmax (chunked: t = t0 + local) ----------------
__global__ __launch_bounds__(256) void k_logits(const float* __restrict__ ae2,
    const float* __restrict__ e, float* __restrict__ out_logits, int* __restrict__ argk, int t0)
{
  __shared__ float es[KK*SS];
  int tid = threadIdx.x;
  for (int i=0;i<4;++i) es[tid + i*256] = e[tid + i*256];
  __syncthreads();
  int g = blockIdx.x*256 + tid;
  int t = t0 + (g >> 10), j = g & 1023;
  const float* arow = &ae2[(size_t)g * SS];
  float a[SS];
  #pragma unroll
  for (int i=0;i<16;++i){ float4 v = ((const float4*)arow)[i]; a[4*i]=v.x; a[4*i+1]=v.y; a[4*i+2]=v.z; a[4*i+3]=v.w; }
  float lg[KK];
  float best = -INFINITY; int bk = 0;
  for (int k=0;k<KK;++k){
    float s2 = 0.f;
    #pragma unroll 8
    for (int s=0;s<SS;++s) s2 += a[s]*es[k*SS+s];
    lg[k] = s2;
    if (s2 > best){ best = s2; bk = k; }
  }
  int n = j >> 7, b = j & 127;
  size_t ob = ((size_t)((t*BB + b)*NN + n)) * KK;
  #pragma unroll
  for (int k4=0;k4<4;++k4)
    *(float4*)&out_logits[ob + k4*4] = make_float4(lg[k4*4],lg[k4*4+1],lg[k4*4+2],lg[k4*4+3]);
  argk[(t*BB + b)*NN + n] = bk;   // stored (b,n)-major: matches reference's prob/q index quirk
}

// ---------------- q selection (chunked) ----------------
__global__ __launch_bounds__(64) void k_qsel(const float* __restrict__ y2,
    const float* __restrict__ w1, const float* __restrict__ b1,
    const int* __restrict__ argk, float* __restrict__ outq)
{
  __shared__ float yr[HH];
  __shared__ float part[64];
  int bj = blockIdx.x;
  int tid = threadIdx.x;
  const float4* row4 = (const float4*)&y2[(size_t)bj*HH];
  ((float4*)yr)[tid]    = row4[tid];
  ((float4*)yr)[tid+64] = row4[tid+64];
  __syncthreads();
  int k = argk[bj];
  int a = tid & 15, q4 = tid >> 4;
  const float* wp = &w1[(size_t)k*HH*AA + a];
  float s = 0.f;
  int h0 = q4*128;
  #pragma unroll 8
  for (int h=h0; h<h0+128; ++h) s += yr[h]*wp[(size_t)h*AA];
  part[tid] = s;
  __syncthreads();
  if (q4 == 0){
    float v = part[a] + part[a+16] + part[a+32] + part[a+48] + b1[k*AA + a];
    outq[(size_t)bj*AA + a] = v;
  }
}

// ---------------- orchestration ----------------
extern "C" void kernel_launch(void* const* d_in, const int* in_sizes, int n_in,
                              void* d_out, int out_size, void* d_ws, size_t ws_size,
                              hipStream_t stream)
{
  (void)in_sizes; (void)n_in; (void)out_size;
  const float* h1     = (const float*)d_in[0];
  const float* h2     = (const float*)d_in[1];
  const float* obs    = (const float*)d_in[2];
  const unsigned char* done_raw = (const unsigned char*)d_in[3];
  const float* W_embed=(const float*)d_in[4];  const float* b_embed=(const float*)d_in[5];
  const float* Wi1    =(const float*)d_in[6];  const float* bi1    =(const float*)d_in[7];
  const float* Wh1    =(const float*)d_in[8];  const float* bhn1   =(const float*)d_in[9];
  const float* W_sub  =(const float*)d_in[10]; const float* b_sub  =(const float*)d_in[11];
  const float* W_e1   =(const float*)d_in[12]; const float* b_e1   =(const float*)d_in[13];
  const float* W_e2   =(const float*)d_in[14]; const float* b_e2   =(const float*)d_in[15];
  const float* W_pol  =(const float*)d_in[16]; const float* b_pol  =(const float*)d_in[17];
  const float* Wi2    =(const float*)d_in[18]; const float* bi2    =(const float*)d_in[19];
  const float* Wh2    =(const float*)d_in[20]; const float* bhn2   =(const float*)d_in[21];
  const float* W_w1   =(const float*)d_in[22]; const float* b_w1   =(const float*)d_in[23];
  const float* W_b1   =(const float*)d_in[24]; const float* b_b1   =(const float*)d_in[25];

  float* out    = (float*)d_out;
  float* outHT1 = out;
  float* outHT2 = out + (size_t)NB*HH;
  float* outQ   = out + 2ull*NB*HH;
  float* outLG  = outQ + (size_t)TT*NB*AA;
  float* outSE  = outLG + (size_t)TT*BB*NN*KK;

  // ---- adaptive chunk size from ws_size ----
  const size_t fixed_f = 2ull*NB*HH /*h_last1,2*/ + (size_t)TT*NB /*mask*/ + 1024 /*e*/
                       + (size_t)KK*HH*AA /*w1*/ + 256 /*b1*/ + (size_t)TT*NB /*argk*/ + 64 /*flag*/;
  const size_t per_t_f = (size_t)NB*(2*HH + 2*H3 + SS);
  int CH = 64;
  while (CH > 1 && (fixed_f + per_t_f*(size_t)CH)*4 > ws_size) CH >>= 1;

  float* buf1   = (float*)d_ws;                        // ae1/y1 chunk: CH*NB*HH
  float* buf2   = buf1   + (size_t)CH*NB*HH;           // sp/y2 chunk
  float* gbuf1  = buf2   + (size_t)CH*NB*HH;           // gi1 chunk: CH*NB*H3
  float* gbuf2  = gbuf1  + (size_t)CH*NB*H3;           // gi2 chunk
  float* ae2buf = gbuf2  + (size_t)CH*NB*H3;           // CH*NB*SS
  float* h_last1= ae2buf + (size_t)CH*NB*SS;
  float* h_last2= h_last1+ (size_t)NB*HH;
  float* maskp  = h_last2+ (size_t)NB*HH;
  float* ws_e   = maskp  + (size_t)TT*NB;
  float* ws_w1  = ws_e   + 1024;
  float* ws_b1  = ws_w1  + (size_t)KK*HH*AA;
  int*   ws_argk= (int*)(ws_b1 + 256);
  int*   ws_flag= (int*)(ws_argk + (size_t)TT*NB);

  // phase 0
  k_detect<<<1,256,0,stream>>>(done_raw, ws_flag);
  k_mask<<<TT*NB/256,256,0,stream>>>(done_raw, ws_flag, maskp);
  k_e<<<1,256,0,stream>>>(W_e1,b_e1,W_e2,b_e2,ws_e);
  k_w1b1<<<128,256,0,stream>>>(ws_e,W_w1,b_w1,W_b1,b_b1,ws_w1,ws_b1);
  k_se<<<2048,256,0,stream>>>(ws_e,outSE);
  k_copy<<<512,256,0,stream>>>(h1, h_last1, NB*HH/4);
  k_copy<<<512,256,0,stream>>>(h2, h_last2, NB*HH/4);

  dim3 thr(256);
  const int NCH = TT / CH;
  for (int c = 0; c < NCH; ++c){
    int t0 = c * CH;
    const float* obs_c = obs + (size_t)t0*NB*DD;
    gemm_bias_act<1><<<dim3(HH/64, CH*NB/64),thr,0,stream>>>(obs_c, W_embed, b_embed, buf1, CH*NB, DD, HH);
    gemm_bias_act<0><<<dim3(H3/64, CH*NB/64),thr,0,stream>>>(buf1, Wi1, bi1, gbuf1, CH*NB, HH, H3);
    gemm_bias_act<1><<<dim3(HH/64, CH*NB/64),thr,0,stream>>>(obs_c, W_pol, b_pol, buf2, CH*NB, DD, HH);
    gemm_bias_act<0><<<dim3(H3/64, CH*NB/64),thr,0,stream>>>(buf2, Wi2, bi2, gbuf2, CH*NB, HH, H3);
    // dual-GRU scan: one launch per step, both GRUs (row-independent => no grid sync needed)
    for (int lt = 0; lt < CH; ++lt){
      const float* hp1 = (lt == 0) ? h_last1 : (buf1 + (size_t)(lt-1)*NB*HH);
      const float* hp2 = (lt == 0) ? h_last2 : (buf2 + (size_t)(lt-1)*NB*HH);
      gru_step2<<<256, 512, 0, stream>>>(hp1, hp2,
                                         gbuf1 + (size_t)lt*NB*H3, gbuf2 + (size_t)lt*NB*H3,
                                         Wh1, Wh2, bhn1, bhn2,
                                         maskp + (size_t)(t0+lt)*NB,
                                         buf1 + (size_t)lt*NB*HH, buf2 + (size_t)lt*NB*HH);
    }
    k_copy<<<512,256,0,stream>>>(buf1 + (size_t)(CH-1)*NB*HH, h_last1, NB*HH/4);
    k_copy<<<512,256,0,stream>>>(buf2 + (size_t)(CH-1)*NB*HH, h_last2, NB*HH/4);
    gemm_bias_act<0><<<dim3(SS/64, CH*NB/64),thr,0,stream>>>(buf1, W_sub, b_sub, ae2buf, CH*NB, HH, SS);
    k_logits<<<CH*NB/256,256,0,stream>>>(ae2buf, ws_e, outLG, ws_argk, t0);
    k_qsel<<<CH*NB,64,0,stream>>>(buf2, ws_w1, ws_b1, ws_argk + (size_t)t0*NB, outQ + (size_t)t0*NB*AA);
  }
  k_copy<<<512,256,0,stream>>>(h_last1, outHT1, NB*HH/4);
  k_copy<<<512,256,0,stream>>>(h_last2, outHT2, NB*HH/4);
}